// Round 3
// baseline (171.693 us; speedup 1.0000x reference)
//
#include <hip/hip_runtime.h>
#include <hip/hip_bf16.h>

// ProbabilisticMap: out[b][x][y][t] = scale(b,t) * exp(-0.5 * d^T inv(cov(b,t)) d),
// d = (x,y) - mean(b,t); mean/cov are Bernstein-weighted sums over <=8 control pts.
//
// Dtype resolution (Round 2 post-mortem): the harness traceback is a source
// LISTING of all decode branches; the "bf16" label text is hard-coded. The
// consistent story across rounds 0-2 is: inputs fp32, num_cps int32, output
// fp32 (reference dtypes taken literally). Runtime detection kept as a cheap
// guard for the (bf16 inputs / int64 num_cps) variants.
//
// Layouts (C-order):
//   cp_means: (K=8, B=128, 2)     fp32 (or bf16 -- detected)
//   num_cps : (B=128,)            int32 (or int64 -- detected)
//   cp_cov  : (K=8, B=128, 2, 2)  fp32 (or bf16 -- detected)
//   out     : (B=128, W=64, H=64, T=64) fp32  -> 128 MiB, write-BW-bound
//
// One block per (b,x). Wave 0 computes per-t stats into LDS (x folded in:
// dx = x - mean_x is block-uniform per t). Then 256 threads stream the (y,t)
// plane: lane = t -> every wave store is 256 B contiguous.

#define MAP_W 64
#define MAP_H 64
#define T_SIZE 64
#define NUM_CP 8
#define BATCH 128

__global__ __launch_bounds__(256) void pmap_kernel(
    const void* __restrict__ cp_means_p,
    const void* __restrict__ num_cps_p,
    const void* __restrict__ cp_cov_p,
    float* __restrict__ out)
{
    // stats[f][t], f in {my, g11, c0, c1, scale}; stride 64 floats -> lane t
    // hits bank t%32: 2 lanes/bank = conflict-free for wave64.
    __shared__ float s_my[T_SIZE], s_g11[T_SIZE], s_c0[T_SIZE], s_c1[T_SIZE], s_sc[T_SIZE];

    const int tid = threadIdx.x;
    const int blk = blockIdx.x;        // blk = b*64 + x
    const int b   = blk >> 6;
    const int x   = blk & 63;

    if (tid < T_SIZE) {
        // ---- runtime dtype detection (wave-uniform, deterministic) ----
        const int* ni32 = (const int*)num_cps_p;
        const bool is_i64 = (ni32[1] == 0);              // values 3..8, never 0
        const int  ncp = is_i64 ? (int)((const long long*)num_cps_p)[b] : ni32[b];
        const int  n   = ncp - 1;                        // 2..7

        const __hip_bfloat16* mbv = (const __hip_bfloat16*)cp_means_p;
        const __hip_bfloat16* cbv = (const __hip_bfloat16*)cp_cov_p;
        const float*          mf  = (const float*)cp_means_p;
        const float*          cf  = (const float*)cp_cov_p;
        // means are in [0,63]; fp32 data viewed as bf16 has random low-halves
        // -> some of the first 32 values falls outside [0,64] (p_miss ~ 5e-10)
        bool is_f32 = false;
        #pragma unroll
        for (int i = 0; i < 32; ++i) {
            const float v = __bfloat162float(mbv[i]);
            if (!(v >= 0.0f && v <= 64.0f)) is_f32 = true;   // NaN lands here too
        }

        // t = linspace(0,1,64)[tid]
        const float t   = (float)tid * (1.0f / 63.0f);
        const float omt = 1.0f - t;

        // Bernstein-weighted mean & covariance, unrolled over k. Binomial via
        // exact small-int recurrence (mul first, then div); (1-t)^(n-k) via
        // unrolled select chain -> register-only.
        float mx = 0.f, my = 0.f, ca = 0.f, cb = 0.f, cc = 0.f, cd = 0.f;
        float ck = 1.0f, tk = 1.0f;
        #pragma unroll
        for (int k = 0; k < NUM_CP; ++k) {
            const int e = n - k;
            float onk = (e == 0) ? 1.0f : 0.0f;
            float o = 1.0f;
            #pragma unroll
            for (int j = 1; j < NUM_CP; ++j) { o *= omt; if (e == j) onk = o; }
            const float w  = (k <= n) ? ck * tk * onk : 0.0f;
            const float w2 = w * w;
            const int base = k * BATCH + b;
            const float m0 = is_f32 ? mf[base*2+0] : __bfloat162float(mbv[base*2+0]);
            const float m1 = is_f32 ? mf[base*2+1] : __bfloat162float(mbv[base*2+1]);
            const float q0 = is_f32 ? cf[base*4+0] : __bfloat162float(cbv[base*4+0]);
            const float q1 = is_f32 ? cf[base*4+1] : __bfloat162float(cbv[base*4+1]);
            const float q2 = is_f32 ? cf[base*4+2] : __bfloat162float(cbv[base*4+2]);
            const float q3 = is_f32 ? cf[base*4+3] : __bfloat162float(cbv[base*4+3]);
            mx = fmaf(w,  m0, mx);
            my = fmaf(w,  m1, my);
            ca = fmaf(w2, q0, ca);
            cb = fmaf(w2, q1, cb);
            cc = fmaf(w2, q2, cc);
            cd = fmaf(w2, q3, cd);
            ck = ck * (float)(n - k) / (float)(k + 1);
            tk *= t;
        }

        // 2x2 inverse folded with -0.5*log2(e) -> inner loop uses native exp2
        const float det     = fmaf(ca, cd, -(cb * cc));  // > 0 (cov >= ~4I/16)
        const float inv_det = 1.0f / det;
        const float HL2E    = 0.72134752044448170368f;   // 0.5 * log2(e)
        const float g00 = -HL2E * cd * inv_det;
        const float gxy =  HL2E * (cb + cc) * inv_det;
        const float g11 = -HL2E * ca * inv_det;
        const float scale = 0.15915494309189535f / sqrtf(det); // 1/(2*pi*sqrt(det))

        // fold block-uniform x into per-t constants
        const float dx = (float)x - mx;
        s_my[tid]  = my;
        s_g11[tid] = g11;
        s_c0[tid]  = g00 * dx * dx;
        s_c1[tid]  = gxy * dx;
        s_sc[tid]  = scale;
    }
    __syncthreads();

    const int t_idx = tid & 63;
    const int y0    = tid >> 6;         // 0..3
    const float my  = s_my[t_idx];
    const float g11 = s_g11[t_idx];
    const float c0  = s_c0[t_idx];
    const float c1  = s_c1[t_idx];
    const float sc  = s_sc[t_idx];

    float* __restrict__ orow = out + ((size_t)blk << 12) + t_idx;

    #pragma unroll
    for (int y = y0; y < MAP_H; y += 4) {
        const float dy  = (float)y - my;
        const float arg = fmaf(dy, fmaf(g11, dy, c1), c0);  // log2-domain quad form
        orow[y << 6] = sc * exp2f(arg);                     // v_exp_f32
    }
}

extern "C" void kernel_launch(void* const* d_in, const int* in_sizes, int n_in,
                              void* d_out, int out_size, void* d_ws, size_t ws_size,
                              hipStream_t stream) {
    pmap_kernel<<<dim3(BATCH * MAP_W), dim3(256), 0, stream>>>(
        d_in[0], d_in[1], d_in[2], (float*)d_out);
}